// Round 8
// baseline (172.760 us; speedup 1.0000x reference)
//
#include <hip/hip_runtime.h>
#include <math.h>

#define NB 32
#define NH 168
#define ND 512
#define NHIST 336
#define NFORE 168
#define NL 504
#define NF 8
#define LOG2E 1.4426950408889634f

__device__ inline float waveSum(float v) {
    #pragma unroll
    for (int m = 1; m < 64; m <<= 1) v += __shfl_xor(v, m, 64);
    return v;
}
__device__ inline float waveMax(float v) {
    #pragma unroll
    for (int m = 1; m < 64; m <<= 1) v = fmaxf(v, __shfl_xor(v, m, 64));
    return v;
}
__device__ inline float grpSum32(float v) {
    v += __shfl_xor(v, 1, 64);
    v += __shfl_xor(v, 2, 64);
    v += __shfl_xor(v, 4, 64);
    v += __shfl_xor(v, 8, 64);
    v += __shfl_xor(v, 16, 64);
    return v;
}
__device__ inline float grpMax32(float v) {
    v = fmaxf(v, __shfl_xor(v, 1, 64));
    v = fmaxf(v, __shfl_xor(v, 2, 64));
    v = fmaxf(v, __shfl_xor(v, 4, 64));
    v = fmaxf(v, __shfl_xor(v, 8, 64));
    v = fmaxf(v, __shfl_xor(v, 16, 64));
    return v;
}
__device__ inline float grpMin32(float v) {
    v = fminf(v, __shfl_xor(v, 1, 64));
    v = fminf(v, __shfl_xor(v, 2, 64));
    v = fminf(v, __shfl_xor(v, 4, 64));
    v = fminf(v, __shfl_xor(v, 8, 64));
    v = fminf(v, __shfl_xor(v, 16, 64));
    return v;
}

// K1 (113 blocks x 256):
//  blk 0..15 : uk[col] = sum_e Wk[e]*Wq[e,col]   (32 cols/block)
//  blk 16..79: wvs[e]=Ws[e,:]·Wv; bvs[e]=8*(Ws[e,:]·bv)+bs[e]  (8 rows/block)
//  blk 80    : ck = bq·Wk
//  blk 81+b  : transpose weather[b] -> xTg[b][f][l], per-(b,f) min/max,
//              and zero finalb[b]/cnt[b]/cnt2[b] (graph-replay safe)
__global__ __launch_bounds__(256) void k_pre(
        const float* __restrict__ wh, const float* __restrict__ wf,
        const float* __restrict__ Wq, const float* __restrict__ bq,
        const float* __restrict__ Wk, const float* __restrict__ Wv,
        const float* __restrict__ bv, const float* __restrict__ Ws,
        const float* __restrict__ bs,
        float* __restrict__ uk, float* __restrict__ wvs,
        float* __restrict__ bvs, float* __restrict__ ckp,
        float* __restrict__ xTg, float* __restrict__ xmxg,
        float* __restrict__ xmng, float* __restrict__ finalb,
        unsigned* __restrict__ cnt, unsigned* __restrict__ cnt2) {
    const int blk = blockIdx.x, tid = threadIdx.x;
    const int lane = tid & 63, w = tid >> 6;
    __shared__ float red[256];
    if (blk < 16) {
        const int col = tid & 31, rg = tid >> 5;       // rg 0..7
        const int colbase = blk << 5;
        float a0 = 0.f, a1 = 0.f, a2 = 0.f, a3 = 0.f;
        #pragma unroll
        for (int r = 0; r < 16; ++r) {
            const int e = rg + 32 * r;                 // 4 interleaved chains
            a0 += Wk[e]      * Wq[e * ND + colbase + col];
            a1 += Wk[e + 8]  * Wq[(e + 8) * ND + colbase + col];
            a2 += Wk[e + 16] * Wq[(e + 16) * ND + colbase + col];
            a3 += Wk[e + 24] * Wq[(e + 24) * ND + colbase + col];
        }
        red[tid] = (a0 + a1) + (a2 + a3);
        __syncthreads();
        if (tid < 32) {
            float s = 0.f;
            #pragma unroll
            for (int i = 0; i < 8; ++i) s += red[i * 32 + tid];
            uk[colbase + tid] = s;
        }
    } else if (blk < 80) {
        const int g = tid >> 5, sl = tid & 31;
        const int e = ((blk - 16) << 3) + g;
        const float4* __restrict__ wsr = (const float4*)(Ws + (size_t)e * ND);
        const float4* __restrict__ wv4 = (const float4*)Wv;
        const float4* __restrict__ bv4 = (const float4*)bv;
        float a1 = 0.f, a2 = 0.f;
        #pragma unroll
        for (int i = 0; i < 4; ++i) {
            const int q = sl + 32 * i;
            const float4 x = wsr[q];
            const float4 v = wv4[q];
            const float4 c = bv4[q];
            a1 += x.x * v.x + x.y * v.y + x.z * v.z + x.w * v.w;
            a2 += x.x * c.x + x.y * c.y + x.z * c.z + x.w * c.w;
        }
        a1 = grpSum32(a1);
        a2 = grpSum32(a2);
        if (sl == 0) { wvs[e] = a1; bvs[e] = 8.f * a2 + bs[e]; }
    } else if (blk == 80) {
        float p = bq[tid] * Wk[tid] + bq[tid + 256] * Wk[tid + 256];
        p = waveSum(p);
        if (lane == 0) red[w] = p;
        __syncthreads();
        if (tid == 0) *ckp = red[0] + red[1] + red[2] + red[3];
    } else {
        const int b = blk - 81;
        // zero the cross-block accumulators for this b (fresh every launch)
        finalb[b * ND + tid] = 0.f;
        finalb[b * ND + tid + 256] = 0.f;
        if (tid == 0) { cnt[b] = 0u; cnt2[b] = 0u; }
        // transpose [l][f] -> xTg[(b*8+f)*504 + l]
        const float4* __restrict__ wh4 = (const float4*)wh;
        const float4* __restrict__ wf4 = (const float4*)wf;
        #pragma unroll
        for (int t = 0; t < 4; ++t) {
            const int j = tid + 256 * t;               // 1008 float4 total
            if (j < NL * 2) {
                const int l = j >> 1, f0 = (j & 1) * 4;
                const float4 v = (l < NHIST)
                    ? wh4[(b * NHIST + l) * 2 + (j & 1)]
                    : wf4[(b * NFORE + (l - NHIST)) * 2 + (j & 1)];
                xTg[(size_t)(b * NF + f0 + 0) * NL + l] = v.x;
                xTg[(size_t)(b * NF + f0 + 1) * NL + l] = v.y;
                xTg[(size_t)(b * NF + f0 + 2) * NL + l] = v.z;
                xTg[(size_t)(b * NF + f0 + 3) * NL + l] = v.w;
            }
        }
        __syncthreads();
        // per-(b,f) min/max readback (L1/L2-hot)
        const int f = tid >> 5, sl = tid & 31;
        const float4* __restrict__ xb = (const float4*)xTg + (size_t)(b * NF + f) * (NL / 4);
        float mx = -1e30f, mn = 1e30f;
        #pragma unroll
        for (int i = 0; i < 4; ++i) {
            const int q = sl + 32 * i;
            if (q < NL / 4) {
                const float4 x = xb[q];
                mx = fmaxf(fmaxf(mx, x.x), fmaxf(x.y, fmaxf(x.z, x.w)));
                mn = fminf(fminf(mn, x.x), fminf(x.y, fminf(x.z, x.w)));
            }
        }
        mx = grpMax32(mx); mn = grpMin32(mn);
        if (sl == 0) { xmxg[b * NF + f] = mx; xmng[b * NF + f] = mn; }
    }
}

// K2 (672 blocks x 256): fused logits + softmax-over-H + final add.
// Per-b lock-free barriers (21 blocks each); y rows held in registers across
// phases so y is read from HBM exactly once.
__global__ __launch_bounds__(256, 4) void k_fused(
        const float* __restrict__ y, const float* __restrict__ xTg,
        const float* __restrict__ xmxg, const float* __restrict__ xmng,
        const float* __restrict__ uk, const float* __restrict__ wvs,
        const float* __restrict__ bvs, const float* __restrict__ ckp,
        float* __restrict__ logits, float* __restrict__ finalb,
        unsigned* __restrict__ cnt, unsigned* __restrict__ cnt2,
        float* __restrict__ out) {
    const int blk = blockIdx.x, tid = threadIdx.x;
    const int b = blk / 21, hb = blk % 21;
    const int slot = tid >> 5, sl = tid & 31;
    const int h = hb * 8 + slot;                       // 0..167 exact
    const float scale = 22.627416997969522f;           // sqrt(512)

    __shared__ float lg[NH];
    __shared__ float mzv[2];
    __shared__ float4 rb[8][32][4];                    // 16 KB slot-reduce buffer

    // ---- phase A: logit for my h; y row stays in yv[] registers ----
    const float4* __restrict__ yr  = (const float4*)(y + ((size_t)b * NH + h) * ND);
    const float4* __restrict__ uk4 = (const float4*)uk;
    const float4* __restrict__ wv4 = (const float4*)wvs;
    const float4* __restrict__ bv4 = (const float4*)bvs;
    float4 yv[4];
    float d1 = 0.f, d2 = 0.f, d3 = 0.f;
    #pragma unroll
    for (int i = 0; i < 4; ++i) {
        const int q = sl + 32 * i;                     // 512B-contig per 32-lane group
        yv[i] = yr[q];
        const float4 u = uk4[q];
        const float4 v = wv4[q];
        const float4 c = bv4[q];
        d1 += yv[i].x * u.x + yv[i].y * u.y + yv[i].z * u.z + yv[i].w * u.w;
        d2 += yv[i].x * v.x + yv[i].y * v.y + yv[i].z * v.z + yv[i].w * v.w;
        d3 += yv[i].x * c.x + yv[i].y * c.y + yv[i].z * c.z + yv[i].w * c.w;
    }
    d1 = grpSum32(d1); d2 = grpSum32(d2); d3 = grpSum32(d3);
    const float a = (d1 + *ckp) / scale;
    const float a2 = a * LOG2E;

    float xmv[NF], xnv[NF];
    #pragma unroll
    for (int f = 0; f < NF; ++f) {
        xmv[f] = xmxg[b * NF + f];
        xnv[f] = xmng[b * NF + f];
    }
    float numf[NF], denf[NF];
    const float4* __restrict__ xb = (const float4*)xTg + (size_t)(b * NF) * (NL / 4);
    #pragma unroll
    for (int f = 0; f < NF; ++f) {
        const float m2 = a2 * ((a >= 0.f) ? xmv[f] : xnv[f]);
        float num = 0.f, den = 0.f;
        #pragma unroll
        for (int i = 0; i < 4; ++i) {
            const int q = sl + 32 * i;
            if (q < NL / 4) {                          // 126 float4
                const float4 x = xb[f * (NL / 4) + q];
                const float e0 = __builtin_amdgcn_exp2f(fmaf(a2, x.x, -m2));
                const float e1 = __builtin_amdgcn_exp2f(fmaf(a2, x.y, -m2));
                const float e2 = __builtin_amdgcn_exp2f(fmaf(a2, x.z, -m2));
                const float e3 = __builtin_amdgcn_exp2f(fmaf(a2, x.w, -m2));
                den += (e0 + e1) + (e2 + e3);
                num += x.x * e0 + x.y * e1;
                num += x.z * e2 + x.w * e3;
            }
        }
        numf[f] = num; denf[f] = den;
    }
    #pragma unroll
    for (int m = 1; m < 32; m <<= 1) {
        #pragma unroll
        for (int f = 0; f < NF; ++f) {
            numf[f] += __shfl_xor(numf[f], m, 64);
            denf[f] += __shfl_xor(denf[f], m, 64);
        }
    }
    float S = 0.f;
    #pragma unroll
    for (int f = 0; f < NF; ++f)
        S += numf[f] * __builtin_amdgcn_rcpf(denf[f]);
    if (sl == 0) logits[b * NH + h] = (S * d2 + d3) / scale;

    // ---- barrier 1: all 21 blocks of b have their logits in memory ----
    __threadfence();
    __syncthreads();
    if (tid == 0) {
        __hip_atomic_fetch_add(&cnt[b], 1u, __ATOMIC_ACQ_REL, __HIP_MEMORY_SCOPE_AGENT);
        while (__hip_atomic_load(&cnt[b], __ATOMIC_ACQUIRE, __HIP_MEMORY_SCOPE_AGENT) < 21u)
            __builtin_amdgcn_s_sleep(1);
    }
    __syncthreads();

    // ---- phase B: P = softmax_H(logits[b]) (redundant per block, cheap) ----
    if (tid < NH) lg[tid] = logits[b * NH + tid];
    __syncthreads();
    if ((tid >> 6) == 0) {
        const int lane = tid & 63;
        float mx = -1e30f;
        for (int i = lane; i < NH; i += 64) mx = fmaxf(mx, lg[i]);
        mx = waveMax(mx);
        float z = 0.f;
        for (int i = lane; i < NH; i += 64) z += __expf(lg[i] - mx);
        z = waveSum(z);
        if (lane == 0) { mzv[0] = mx; mzv[1] = 1.f / z; }
    }
    __syncthreads();
    if (tid < NH) lg[tid] = __expf(lg[tid] - mzv[0]) * mzv[1];   // lg := P
    __syncthreads();

    // ---- phase C: partial final = sum over my 8 h of P[h]*y (regs) ----
    const float Ph = lg[h];
    #pragma unroll
    for (int i = 0; i < 4; ++i) {
        float4 p;
        p.x = Ph * yv[i].x; p.y = Ph * yv[i].y;
        p.z = Ph * yv[i].z; p.w = Ph * yv[i].w;
        rb[slot][sl][i] = p;
    }
    __syncthreads();
    if (slot == 0) {
        #pragma unroll
        for (int i = 0; i < 4; ++i) {
            float4 s = rb[0][sl][i];
            #pragma unroll
            for (int s2 = 1; s2 < 8; ++s2) {
                const float4 t = rb[s2][sl][i];
                s.x += t.x; s.y += t.y; s.z += t.z; s.w += t.w;
            }
            const int dbase = (sl + 32 * i) * 4;
            atomicAdd(&finalb[b * ND + dbase + 0], s.x);
            atomicAdd(&finalb[b * ND + dbase + 1], s.y);
            atomicAdd(&finalb[b * ND + dbase + 2], s.z);
            atomicAdd(&finalb[b * ND + dbase + 3], s.w);
        }
    }

    // ---- barrier 2: finalb[b] complete ----
    __threadfence();
    __syncthreads();
    if (tid == 0) {
        __hip_atomic_fetch_add(&cnt2[b], 1u, __ATOMIC_ACQ_REL, __HIP_MEMORY_SCOPE_AGENT);
        while (__hip_atomic_load(&cnt2[b], __ATOMIC_ACQUIRE, __HIP_MEMORY_SCOPE_AGENT) < 21u)
            __builtin_amdgcn_s_sleep(1);
    }
    __syncthreads();

    // ---- phase D: out = y(regs) + final[b] ----
    const float4* __restrict__ f4 = (const float4*)(finalb + b * ND);
    float4* __restrict__ out4 = (float4*)out;
    const size_t obase = ((size_t)b * NH + h) * 128;
    #pragma unroll
    for (int i = 0; i < 4; ++i) {
        const int q = sl + 32 * i;
        const float4 fin = f4[q];
        float4 o = yv[i];
        o.x += fin.x; o.y += fin.y; o.z += fin.z; o.w += fin.w;
        out4[obase + q] = o;
    }
}

extern "C" void kernel_launch(void* const* d_in, const int* in_sizes, int n_in,
                              void* d_out, int out_size, void* d_ws, size_t ws_size,
                              hipStream_t stream) {
    const float* y  = (const float*)d_in[0];
    const float* wh = (const float*)d_in[1];
    const float* wf = (const float*)d_in[2];
    const float* Wq = (const float*)d_in[3];
    const float* bq = (const float*)d_in[4];
    const float* Wk = (const float*)d_in[5];
    // d_in[6] = bk: cancels in the softmax over L — unused.
    const float* Wv = (const float*)d_in[7];
    const float* bv = (const float*)d_in[8];
    const float* Ws = (const float*)d_in[9];
    const float* bs = (const float*)d_in[10];
    float* out = (float*)d_out;
    float* ws = (float*)d_ws;

    float*    uk     = ws;                      // 512
    float*    wvs    = ws + 512;                // 512
    float*    bvs    = ws + 1024;               // 512
    float*    ckp    = ws + 1536;               // 1
    float*    logits = ws + 1600;               // 5376
    float*    xTg    = ws + 8192;               // 129024
    float*    xmxg   = ws + 137216;             // 256
    float*    xmng   = ws + 137472;             // 256
    unsigned* cnt    = (unsigned*)(ws + 137728);  // 32
    unsigned* cnt2   = (unsigned*)(ws + 137760);  // 32
    float*    finalb = ws + 137792;             // 16384 (16B-aligned)

    k_pre<<<113, 256, 0, stream>>>(wh, wf, Wq, bq, Wk, Wv, bv, Ws, bs,
                                   uk, wvs, bvs, ckp, xTg, xmxg, xmng,
                                   finalb, cnt, cnt2);
    k_fused<<<NB * 21, 256, 0, stream>>>(y, xTg, xmxg, xmng, uk, wvs, bvs, ckp,
                                         logits, finalb, cnt, cnt2, out);
}

// Round 9
// 29.563 us; speedup vs baseline: 5.8438x; 5.8438x over previous
//
#include <hip/hip_runtime.h>
#include <math.h>

#define NB 32
#define NH 168
#define ND 512
#define NHIST 336
#define NFORE 168
#define NL 504
#define NF 8
#define LOG2E 1.4426950408889634f

__device__ inline float waveSum(float v) {
    #pragma unroll
    for (int m = 1; m < 64; m <<= 1) v += __shfl_xor(v, m, 64);
    return v;
}
__device__ inline float grpSum32(float v) {
    v += __shfl_xor(v, 1, 64);
    v += __shfl_xor(v, 2, 64);
    v += __shfl_xor(v, 4, 64);
    v += __shfl_xor(v, 8, 64);
    v += __shfl_xor(v, 16, 64);
    return v;
}

// K1 (113 blocks x 256):
//  blk 0..15 : uk[col] = sum_e Wk[e]*Wq[e,col]   (32 cols/block)
//  blk 16..79: wvs[e]=Ws[e,:]·Wv; bvs[e]=8*(Ws[e,:]·bv)+bs[e]  (8 rows/block)
//  blk 80    : ck = bq·Wk
//  blk 81+b  : zero num[b,:]/den[b] (graph-replay safe: re-zeroed every launch)
__global__ __launch_bounds__(256) void k_pre(
        const float* __restrict__ Wq, const float* __restrict__ bq,
        const float* __restrict__ Wk, const float* __restrict__ Wv,
        const float* __restrict__ bv, const float* __restrict__ Ws,
        const float* __restrict__ bs,
        float* __restrict__ uk, float* __restrict__ wvs,
        float* __restrict__ bvs, float* __restrict__ ckp,
        float* __restrict__ num, float* __restrict__ den) {
    const int blk = blockIdx.x, tid = threadIdx.x;
    const int lane = tid & 63, w = tid >> 6;
    __shared__ float red[256];
    if (blk < 16) {
        const int col = tid & 31, rg = tid >> 5;       // rg 0..7
        const int colbase = blk << 5;
        float a0 = 0.f, a1 = 0.f, a2 = 0.f, a3 = 0.f;
        #pragma unroll
        for (int r = 0; r < 16; ++r) {
            const int e = rg + 32 * r;                 // 4 interleaved chains
            a0 += Wk[e]      * Wq[e * ND + colbase + col];
            a1 += Wk[e + 8]  * Wq[(e + 8) * ND + colbase + col];
            a2 += Wk[e + 16] * Wq[(e + 16) * ND + colbase + col];
            a3 += Wk[e + 24] * Wq[(e + 24) * ND + colbase + col];
        }
        red[tid] = (a0 + a1) + (a2 + a3);
        __syncthreads();
        if (tid < 32) {
            float s = 0.f;
            #pragma unroll
            for (int i = 0; i < 8; ++i) s += red[i * 32 + tid];
            uk[colbase + tid] = s;
        }
    } else if (blk < 80) {
        const int g = tid >> 5, sl = tid & 31;
        const int e = ((blk - 16) << 3) + g;
        const float4* __restrict__ wsr = (const float4*)(Ws + (size_t)e * ND);
        const float4* __restrict__ wv4 = (const float4*)Wv;
        const float4* __restrict__ bv4 = (const float4*)bv;
        float a1 = 0.f, a2 = 0.f;
        #pragma unroll
        for (int i = 0; i < 4; ++i) {
            const int q = sl + 32 * i;
            const float4 x = wsr[q];
            const float4 v = wv4[q];
            const float4 c = bv4[q];
            a1 += x.x * v.x + x.y * v.y + x.z * v.z + x.w * v.w;
            a2 += x.x * c.x + x.y * c.y + x.z * c.z + x.w * c.w;
        }
        a1 = grpSum32(a1);
        a2 = grpSum32(a2);
        if (sl == 0) { wvs[e] = a1; bvs[e] = 8.f * a2 + bs[e]; }
    } else if (blk == 80) {
        float p = bq[tid] * Wk[tid] + bq[tid + 256] * Wk[tid + 256];
        p = waveSum(p);
        if (lane == 0) red[w] = p;
        __syncthreads();
        if (tid == 0) *ckp = red[0] + red[1] + red[2] + red[3];
    } else {
        const int b = blk - 81;
        num[b * ND + tid] = 0.f;
        num[b * ND + tid + 256] = 0.f;
        if (tid == 0) den[b] = 0.f;
    }
}

// K2 (672 blocks x 256): per (b,h) logit -> unnormalized H-softmax weight
// wexp = e^logit; atomically accumulate num[b,:] += wexp*y_row, den[b] += wexp.
// Weather read RAW from global (L2-resident, no transpose, no minmax).
__global__ __launch_bounds__(256) void k_main(
        const float* __restrict__ y, const float* __restrict__ wh,
        const float* __restrict__ wf,
        const float* __restrict__ uk, const float* __restrict__ wvs,
        const float* __restrict__ bvs, const float* __restrict__ ckp,
        float* __restrict__ num, float* __restrict__ den) {
    const int blk = blockIdx.x, tid = threadIdx.x;
    const int b = blk / 21, hb = blk % 21;
    const int slot = tid >> 5, sl = tid & 31;
    const int h = hb * 8 + slot;                       // 0..167 exact
    const float scale = 22.627416997969522f;           // sqrt(512)

    // ---- dots d1,d2,d3 over the y row (kept in regs) ----
    const float4* __restrict__ yr  = (const float4*)(y + ((size_t)b * NH + h) * ND);
    const float4* __restrict__ uk4 = (const float4*)uk;
    const float4* __restrict__ wv4 = (const float4*)wvs;
    const float4* __restrict__ bv4 = (const float4*)bvs;
    float4 yv[4];
    float d1 = 0.f, d2 = 0.f, d3 = 0.f;
    #pragma unroll
    for (int i = 0; i < 4; ++i) {
        const int q = sl + 32 * i;                     // 512B-contig per 32-lane group
        yv[i] = yr[q];
        const float4 u = uk4[q];
        const float4 v = wv4[q];
        const float4 c = bv4[q];
        d1 += yv[i].x * u.x + yv[i].y * u.y + yv[i].z * u.z + yv[i].w * u.w;
        d2 += yv[i].x * v.x + yv[i].y * v.y + yv[i].z * v.z + yv[i].w * v.w;
        d3 += yv[i].x * c.x + yv[i].y * c.y + yv[i].z * c.z + yv[i].w * c.w;
    }
    d1 = grpSum32(d1); d2 = grpSum32(d2); d3 = grpSum32(d3);
    const float a = (d1 + *ckp) / scale;
    const float a2 = a * LOG2E;

    // ---- weather loop, raw layout [l][f], no max subtraction ----
    const float4* __restrict__ whp = (const float4*)(wh + (size_t)b * NHIST * NF);
    const float4* __restrict__ wfp = (const float4*)(wf + (size_t)b * NFORE * NF);
    float numf[NF], denf[NF];
    #pragma unroll
    for (int f = 0; f < NF; ++f) { numf[f] = 0.f; denf[f] = 0.f; }
    #pragma unroll
    for (int i = 0; i < 16; ++i) {
        const int l = sl + 32 * i;
        if (l < NL) {                                  // i<15 always; i==15: sl<24
            const float4* __restrict__ src =
                (l < NHIST) ? (whp + (size_t)l * 2) : (wfp + (size_t)(l - NHIST) * 2);
            const float4 xa = src[0];
            const float4 xb = src[1];
            const float e0 = __builtin_amdgcn_exp2f(a2 * xa.x);
            const float e1 = __builtin_amdgcn_exp2f(a2 * xa.y);
            const float e2 = __builtin_amdgcn_exp2f(a2 * xa.z);
            const float e3 = __builtin_amdgcn_exp2f(a2 * xa.w);
            const float e4 = __builtin_amdgcn_exp2f(a2 * xb.x);
            const float e5 = __builtin_amdgcn_exp2f(a2 * xb.y);
            const float e6 = __builtin_amdgcn_exp2f(a2 * xb.z);
            const float e7 = __builtin_amdgcn_exp2f(a2 * xb.w);
            numf[0] += xa.x * e0; denf[0] += e0;
            numf[1] += xa.y * e1; denf[1] += e1;
            numf[2] += xa.z * e2; denf[2] += e2;
            numf[3] += xa.w * e3; denf[3] += e3;
            numf[4] += xb.x * e4; denf[4] += e4;
            numf[5] += xb.y * e5; denf[5] += e5;
            numf[6] += xb.z * e6; denf[6] += e6;
            numf[7] += xb.w * e7; denf[7] += e7;
        }
    }
    #pragma unroll
    for (int m = 1; m < 32; m <<= 1) {
        #pragma unroll
        for (int f = 0; f < NF; ++f) {
            numf[f] += __shfl_xor(numf[f], m, 64);
            denf[f] += __shfl_xor(denf[f], m, 64);
        }
    }
    float S = 0.f;
    #pragma unroll
    for (int f = 0; f < NF; ++f)
        S += numf[f] * __builtin_amdgcn_rcpf(denf[f]);
    const float logit = (S * d2 + d3) / scale;
    const float wexp = __builtin_amdgcn_exp2f(logit * LOG2E);  // unnormalized P

    // ---- block-level reduce of wexp*y across the 8 slots, then atomics ----
    __shared__ float4 rb[8][32][4];                    // 16 KB
    __shared__ float dsl[8];
    #pragma unroll
    for (int i = 0; i < 4; ++i) {
        float4 p;
        p.x = wexp * yv[i].x; p.y = wexp * yv[i].y;
        p.z = wexp * yv[i].z; p.w = wexp * yv[i].w;
        rb[slot][sl][i] = p;
    }
    if (sl == 0) dsl[slot] = wexp;
    __syncthreads();
    if (tid < 128) {
        const int c = tid & 31, i = tid >> 5;
        float4 s = rb[0][c][i];
        #pragma unroll
        for (int s2 = 1; s2 < 8; ++s2) {
            const float4 t = rb[s2][c][i];
            s.x += t.x; s.y += t.y; s.z += t.z; s.w += t.w;
        }
        const int dbase = b * ND + (c + 32 * i) * 4;
        atomicAdd(&num[dbase + 0], s.x);
        atomicAdd(&num[dbase + 1], s.y);
        atomicAdd(&num[dbase + 2], s.z);
        atomicAdd(&num[dbase + 3], s.w);
    }
    if (tid == 0) {
        float s = 0.f;
        #pragma unroll
        for (int i = 0; i < 8; ++i) s += dsl[i];
        atomicAdd(&den[b], s);
    }
}

// K3 (512 blocks x 256): out[b,h,:] = y[b,h,:] + num[b,:]/den[b].
__global__ __launch_bounds__(256) void k_final(
        const float* __restrict__ y, const float* __restrict__ num,
        const float* __restrict__ den, float* __restrict__ out) {
    const int b = blockIdx.x >> 4, dc = blockIdx.x & 15;
    const int tid = threadIdx.x;
    __shared__ float4 fin[8];
    __shared__ float invd;
    if (tid == 0) invd = 1.f / den[b];
    if (tid < 8) fin[tid] = ((const float4*)num)[b * 128 + dc * 8 + tid];
    __syncthreads();
    const int c = tid & 7, hw = tid >> 3;              // 8 float4 cols, 32 h-groups
    const float id = invd;
    float4 F = fin[c];
    F.x *= id; F.y *= id; F.z *= id; F.w *= id;
    const float4* __restrict__ y4 = (const float4*)y;
    float4* __restrict__ out4 = (float4*)out;
    const size_t base = ((size_t)b * NH) * 128 + dc * 8 + c;
    #pragma unroll
    for (int k = 0; k < 6; ++k) {
        const int hh = hw + 32 * k;
        if (hh < NH) {
            float4 o = y4[base + (size_t)hh * 128];
            o.x += F.x; o.y += F.y; o.z += F.z; o.w += F.w;
            out4[base + (size_t)hh * 128] = o;
        }
    }
}

extern "C" void kernel_launch(void* const* d_in, const int* in_sizes, int n_in,
                              void* d_out, int out_size, void* d_ws, size_t ws_size,
                              hipStream_t stream) {
    const float* y  = (const float*)d_in[0];
    const float* wh = (const float*)d_in[1];
    const float* wf = (const float*)d_in[2];
    const float* Wq = (const float*)d_in[3];
    const float* bq = (const float*)d_in[4];
    const float* Wk = (const float*)d_in[5];
    // d_in[6] = bk: cancels in the softmax over L — unused.
    const float* Wv = (const float*)d_in[7];
    const float* bv = (const float*)d_in[8];
    const float* Ws = (const float*)d_in[9];
    const float* bs = (const float*)d_in[10];
    float* out = (float*)d_out;
    float* ws = (float*)d_ws;

    float* uk  = ws;                 // 512
    float* wvs = ws + 512;           // 512
    float* bvs = ws + 1024;          // 512
    float* ckp = ws + 1536;          // 1 (padded to 512)
    float* num = ws + 2048;          // 32*512 = 16384 (16B-aligned)
    float* den = ws + 2048 + 16384;  // 32

    k_pre<<<113, 256, 0, stream>>>(Wq, bq, Wk, Wv, bv, Ws, bs,
                                   uk, wvs, bvs, ckp, num, den);
    k_main<<<NB * 21, 256, 0, stream>>>(y, wh, wf, uk, wvs, bvs, ckp, num, den);
    k_final<<<NB * 16, 256, 0, stream>>>(y, num, den, out);
}

// Round 10
// 24.279 us; speedup vs baseline: 7.1157x; 1.2177x over previous
//
#include <hip/hip_runtime.h>
#include <math.h>

#define NB 32
#define NH 168
#define ND 512
#define NHIST 336
#define NFORE 168
#define NL 504
#define NF 8
#define LOG2E 1.4426950408889634f
#define SCALE 22.627416997969522f   // sqrt(512)

__device__ inline float waveSum(float v) {
    #pragma unroll
    for (int m = 1; m < 64; m <<= 1) v += __shfl_xor(v, m, 64);
    return v;
}
__device__ inline float grpSum32(float v) {
    v += __shfl_xor(v, 1, 64);
    v += __shfl_xor(v, 2, 64);
    v += __shfl_xor(v, 4, 64);
    v += __shfl_xor(v, 8, 64);
    v += __shfl_xor(v, 16, 64);
    return v;
}

// K1 (97 blocks x 256): weights only, scale factors pre-folded.
//  blk 0..31 : uk2[col] = (LOG2E/SCALE) * sum_e Wk[e]*Wq[e,col]  (16 cols/block)
//  blk 32..95: wvs2[e]=Ws[e,:]·Wv/SCALE; bvs2[e]=(8*(Ws[e,:]·bv)+bs[e])/SCALE
//  blk 96    : ck2 = (bq·Wk)*LOG2E/SCALE
__global__ __launch_bounds__(256) void k_pre(
        const float* __restrict__ Wq, const float* __restrict__ bq,
        const float* __restrict__ Wk, const float* __restrict__ Wv,
        const float* __restrict__ bv, const float* __restrict__ Ws,
        const float* __restrict__ bs,
        float* __restrict__ uk2, float* __restrict__ wvs2,
        float* __restrict__ bvs2, float* __restrict__ ckp) {
    const int blk = blockIdx.x, tid = threadIdx.x;
    __shared__ float red[256];
    if (blk < 32) {
        const int c = tid & 15, rg = tid >> 4;         // 16 cols, 16 row-groups
        const int colbase = blk << 4;
        float acc = 0.f;
        #pragma unroll
        for (int r = 0; r < 32; ++r) {                 // 32 independent loads
            const int e = rg + 16 * r;
            acc += Wk[e] * Wq[e * ND + colbase + c];
        }
        red[rg * 16 + c] = acc;
        __syncthreads();
        if (tid < 16) {
            float s = 0.f;
            #pragma unroll
            for (int i = 0; i < 16; ++i) s += red[i * 16 + tid];
            uk2[colbase + tid] = s * (LOG2E / SCALE);
        }
    } else if (blk < 96) {
        const int g = tid >> 5, sl = tid & 31;         // 8 rows, 32 lanes each
        const int e = ((blk - 32) << 3) + g;
        const float4* __restrict__ wsr = (const float4*)(Ws + (size_t)e * ND);
        const float4* __restrict__ wv4 = (const float4*)Wv;
        const float4* __restrict__ bv4 = (const float4*)bv;
        float a1 = 0.f, a2 = 0.f;
        #pragma unroll
        for (int i = 0; i < 4; ++i) {
            const int q = sl + 32 * i;
            const float4 x = wsr[q];
            const float4 v = wv4[q];
            const float4 c = bv4[q];
            a1 += x.x * v.x + x.y * v.y + x.z * v.z + x.w * v.w;
            a2 += x.x * c.x + x.y * c.y + x.z * c.z + x.w * c.w;
        }
        a1 = grpSum32(a1);
        a2 = grpSum32(a2);
        if (sl == 0) {
            wvs2[e] = a1 * (1.f / SCALE);
            bvs2[e] = (8.f * a2 + bs[e]) * (1.f / SCALE);
        }
    } else {
        const int lane = tid & 63, w = tid >> 6;
        float p = bq[tid] * Wk[tid] + bq[tid + 256] * Wk[tid + 256];
        p = waveSum(p);
        if (lane == 0) red[w] = p;
        __syncthreads();
        if (tid == 0)
            *ckp = (red[0] + red[1] + red[2] + red[3]) * (LOG2E / SCALE);
    }
}

// K2 (672 blocks x 256): logits. No LDS, no atomics, weather raw from L2.
// 32 lanes per h, 8 h per block.
__global__ __launch_bounds__(256) void k_main(
        const float* __restrict__ y, const float* __restrict__ wh,
        const float* __restrict__ wf,
        const float* __restrict__ uk2, const float* __restrict__ wvs2,
        const float* __restrict__ bvs2, const float* __restrict__ ckp,
        float* __restrict__ logits) {
    const int blk = blockIdx.x, tid = threadIdx.x;
    const int b = blk / 21, hb = blk % 21;
    const int slot = tid >> 5, sl = tid & 31;
    const int h = hb * 8 + slot;                       // 0..167 exact

    // ---- dots over the y row ----
    const float4* __restrict__ yr  = (const float4*)(y + ((size_t)b * NH + h) * ND);
    const float4* __restrict__ uk4 = (const float4*)uk2;
    const float4* __restrict__ wv4 = (const float4*)wvs2;
    const float4* __restrict__ bv4 = (const float4*)bvs2;
    float d1 = 0.f, d2 = 0.f, d3 = 0.f;
    #pragma unroll
    for (int i = 0; i < 4; ++i) {
        const int q = sl + 32 * i;                     // 512B-contig per 32-lane group
        const float4 yv = yr[q];
        const float4 u = uk4[q];
        const float4 v = wv4[q];
        const float4 c = bv4[q];
        d1 += yv.x * u.x + yv.y * u.y + yv.z * u.z + yv.w * u.w;
        d2 += yv.x * v.x + yv.y * v.y + yv.z * v.z + yv.w * v.w;
        d3 += yv.x * c.x + yv.y * c.y + yv.z * c.z + yv.w * c.w;
    }
    d1 = grpSum32(d1); d2 = grpSum32(d2); d3 = grpSum32(d3);
    const float a2 = d1 + *ckp;                        // = a * LOG2E (pre-scaled)

    // ---- weather loop, raw [l][f] layout, unnormalized softmax over l ----
    const float4* __restrict__ whp = (const float4*)(wh + (size_t)b * NHIST * NF);
    const float4* __restrict__ wfp = (const float4*)(wf + (size_t)b * NFORE * NF);
    float numf[NF], denf[NF];
    #pragma unroll
    for (int f = 0; f < NF; ++f) { numf[f] = 0.f; denf[f] = 0.f; }
    #pragma unroll
    for (int i = 0; i < 16; ++i) {
        const int l = sl + 32 * i;
        if (l < NL) {                                  // i<15 always; i==15: sl<24
            const float4* __restrict__ src =
                (l < NHIST) ? (whp + (size_t)l * 2) : (wfp + (size_t)(l - NHIST) * 2);
            const float4 xa = src[0];
            const float4 xb = src[1];
            const float e0 = __builtin_amdgcn_exp2f(a2 * xa.x);
            const float e1 = __builtin_amdgcn_exp2f(a2 * xa.y);
            const float e2 = __builtin_amdgcn_exp2f(a2 * xa.z);
            const float e3 = __builtin_amdgcn_exp2f(a2 * xa.w);
            const float e4 = __builtin_amdgcn_exp2f(a2 * xb.x);
            const float e5 = __builtin_amdgcn_exp2f(a2 * xb.y);
            const float e6 = __builtin_amdgcn_exp2f(a2 * xb.z);
            const float e7 = __builtin_amdgcn_exp2f(a2 * xb.w);
            numf[0] += xa.x * e0; denf[0] += e0;
            numf[1] += xa.y * e1; denf[1] += e1;
            numf[2] += xa.z * e2; denf[2] += e2;
            numf[3] += xa.w * e3; denf[3] += e3;
            numf[4] += xb.x * e4; denf[4] += e4;
            numf[5] += xb.y * e5; denf[5] += e5;
            numf[6] += xb.z * e6; denf[6] += e6;
            numf[7] += xb.w * e7; denf[7] += e7;
        }
    }
    #pragma unroll
    for (int m = 1; m < 32; m <<= 1) {
        #pragma unroll
        for (int f = 0; f < NF; ++f) {
            numf[f] += __shfl_xor(numf[f], m, 64);
            denf[f] += __shfl_xor(denf[f], m, 64);
        }
    }
    float S = 0.f;
    #pragma unroll
    for (int f = 0; f < NF; ++f)
        S += numf[f] * __builtin_amdgcn_rcpf(denf[f]);
    if (sl == 0) logits[b * NH + h] = S * d2 + d3;     // already /SCALE
}

// K3 (512 blocks x 256): per (b, 128B d-chunk): unnormalized softmax over H,
// final = (sum_h e^l[h] * y[b,h,:]) / (sum_h e^l[h]); out = y + final.
__global__ __launch_bounds__(256) void k_final(
        const float* __restrict__ y, const float* __restrict__ logits,
        float* __restrict__ out) {
    const int b = blockIdx.x >> 4, dc = blockIdx.x & 15;
    const int tid = threadIdx.x, lane = tid & 63, w = tid >> 6;
    __shared__ float el[NH];
    __shared__ float invz;
    __shared__ float4 fl4[32];
    __shared__ float4 ffin[8];
    if (tid < NH)
        el[tid] = __builtin_amdgcn_exp2f(logits[b * NH + tid] * LOG2E);
    __syncthreads();
    if (w == 0) {
        float z = 0.f;
        for (int i = lane; i < NH; i += 64) z += el[i];
        z = waveSum(z);
        if (lane == 0) invz = 1.f / z;
    }
    __syncthreads();

    const int c = tid & 7, hw = tid >> 3;              // 8 float4 cols, 32 h-groups
    const float4* __restrict__ y4 = (const float4*)y;
    const size_t base = ((size_t)b * NH) * 128 + dc * 8 + c;
    float4 acc = make_float4(0.f, 0.f, 0.f, 0.f);
    #pragma unroll
    for (int k = 0; k < 6; ++k) {
        const int hh = hw + 32 * k;
        if (hh < NH) {
            const float4 yv = y4[base + (size_t)hh * 128];
            const float P = el[hh];                    // unnormalized
            acc.x += P * yv.x; acc.y += P * yv.y;
            acc.z += P * yv.z; acc.w += P * yv.w;
        }
    }
    #pragma unroll
    for (int m = 8; m < 64; m <<= 1) {                 // lane bits 3,4,5
        acc.x += __shfl_xor(acc.x, m, 64);
        acc.y += __shfl_xor(acc.y, m, 64);
        acc.z += __shfl_xor(acc.z, m, 64);
        acc.w += __shfl_xor(acc.w, m, 64);
    }
    if (lane < 8) fl4[w * 8 + lane] = acc;
    __syncthreads();
    if (tid < 8) {
        float4 s = fl4[tid];
        #pragma unroll
        for (int i = 1; i < 4; ++i) {
            const float4 t = fl4[i * 8 + tid];
            s.x += t.x; s.y += t.y; s.z += t.z; s.w += t.w;
        }
        const float iz = invz;
        s.x *= iz; s.y *= iz; s.z *= iz; s.w *= iz;
        ffin[tid] = s;
    }
    __syncthreads();
    const float4 fin = ffin[c];
    float4* __restrict__ out4 = (float4*)out;
    #pragma unroll
    for (int k = 0; k < 6; ++k) {
        const int hh = hw + 32 * k;
        if (hh < NH) {
            float4 o = y4[base + (size_t)hh * 128];
            o.x += fin.x; o.y += fin.y; o.z += fin.z; o.w += fin.w;
            out4[base + (size_t)hh * 128] = o;
        }
    }
}

extern "C" void kernel_launch(void* const* d_in, const int* in_sizes, int n_in,
                              void* d_out, int out_size, void* d_ws, size_t ws_size,
                              hipStream_t stream) {
    const float* y  = (const float*)d_in[0];
    const float* wh = (const float*)d_in[1];
    const float* wf = (const float*)d_in[2];
    const float* Wq = (const float*)d_in[3];
    const float* bq = (const float*)d_in[4];
    const float* Wk = (const float*)d_in[5];
    // d_in[6] = bk: cancels in the softmax over L — unused.
    const float* Wv = (const float*)d_in[7];
    const float* bv = (const float*)d_in[8];
    const float* Ws = (const float*)d_in[9];
    const float* bs = (const float*)d_in[10];
    float* out = (float*)d_out;
    float* ws = (float*)d_ws;

    float* uk2  = ws;            // 512
    float* wvs2 = ws + 512;      // 512
    float* bvs2 = ws + 1024;     // 512
    float* ckp  = ws + 1536;     // 1 (padded)
    float* logits = ws + 2048;   // 5376

    k_pre<<<97, 256, 0, stream>>>(Wq, bq, Wk, Wv, bv, Ws, bs,
                                  uk2, wvs2, bvs2, ckp);
    k_main<<<NB * 21, 256, 0, stream>>>(y, wh, wf, uk2, wvs2, bvs2, ckp, logits);
    k_final<<<NB * 16, 256, 0, stream>>>(y, logits, out);
}